// Round 5
// baseline (24871.315 us; speedup 1.0000x reference)
//
#include <hip/hip_runtime.h>

#define BATCH 1024
#define SEQ 512
#define NFEAT 24
#define NCELL 512
#define ZC 2048      // 4*NCELL
#define KP 544       // reordered K: [h(512) | x(24) | pad(8)]
#define NCH 17       // K chunks of 32
#define KL 552       // LDS k-stride in u16 (pad for bank spread)
#define DENSE_N 2048
#define PRED_N 576
#define NWG 256

typedef unsigned short u16;
typedef unsigned short u16x8 __attribute__((ext_vector_type(8)));
typedef short s16x8 __attribute__((ext_vector_type(8)));
typedef float f32x4 __attribute__((ext_vector_type(4)));

__device__ __forceinline__ float sigm(float x) { return 1.f / (1.f + __expf(-x)); }
__device__ __forceinline__ float ftanh(float x) {
    float t = __expf(-2.f * fabsf(x));
    float r = (1.f - t) / (1.f + t);
    return copysignf(r, x);
}
__device__ __forceinline__ u16 f2b(float v) {           // f32 -> bf16 RTNE
    unsigned int x = __float_as_uint(v);
    unsigned int r = (x + 0x7fffu + ((x >> 16) & 1u)) >> 16;
    return (u16)r;
}
__device__ __forceinline__ float b2f(u16 u) { return __uint_as_float(((unsigned int)u) << 16); }

// ---------- prep: W -> transposed, K-reordered, split hi/lo ----------
__global__ __launch_bounds__(256) void prep_w(const float* __restrict__ W,
                                              u16* __restrict__ Whi, u16* __restrict__ Wlo) {
    int o = blockIdx.x * 256 + threadIdx.x;            // over ZC*KP
    if (o >= ZC * KP) return;
    int n = o / KP, k = o % KP;
    float v = 0.f;
    if (k < NCELL)              v = W[(size_t)(NFEAT + k) * ZC + n];   // h rows
    else if (k < NCELL + NFEAT) v = W[(size_t)(k - NCELL) * ZC + n];   // x rows
    u16 hi = f2b(v);
    u16 lo = f2b(v - b2f(hi));
    Whi[o] = hi; Wlo[o] = lo;
}

// ---------- prep: H0 = [h=0 | x_0 | 0], H1 = 0 ----------
__global__ __launch_bounds__(256) void prep_h(const float* __restrict__ X,
                                              u16* __restrict__ H0hi, u16* __restrict__ H0lo,
                                              u16* __restrict__ H1hi, u16* __restrict__ H1lo) {
    int o = blockIdx.x * 256 + threadIdx.x;            // over BATCH*KP
    if (o >= BATCH * KP) return;
    int row = o / KP, k = o % KP;
    u16 hi = 0, lo = 0;
    if (k >= NCELL && k < NCELL + NFEAT) {
        float v = X[(size_t)row * (SEQ * NFEAT) + (k - NCELL)];  // t = 0
        hi = f2b(v); lo = f2b(v - b2f(hi));
    }
    H0hi[o] = hi; H0lo[o] = lo;
    H1hi[o] = 0;  H1lo[o] = 0;
}

// ---------- persistent LSTM: all 512 steps in one kernel ----------
// Grid = 256 WGs (1/CU). WG = (nb, rb): nb = 64 z-cols (16 cells x 4 gates),
// rb = 128 batch rows. W slice resident in LDS; c resident in registers;
// H ping-pong in global; manual grid barrier per step.
__global__ __launch_bounds__(256, 1) void lstm_persist(
    u16* __restrict__ H0hi, u16* __restrict__ H0lo,
    u16* __restrict__ H1hi, u16* __restrict__ H1lo,
    const u16* __restrict__ Wthi, const u16* __restrict__ Wtlo,  // [ZC][KP]
    const float* __restrict__ bias,                              // [ZC]
    const float* __restrict__ X,                                 // [BATCH][SEQ][NFEAT]
    float* __restrict__ hf32,                                    // [BATCH][NCELL]
    int* __restrict__ bar_cnt, int* __restrict__ bar_epoch)
{
    extern __shared__ u16 Ws[];   // [2 planes][64 cols][KL]

    const int tid = (int)threadIdx.x;
    const int bid = (int)blockIdx.x;
    const int nb = bid & 31, rb = bid >> 5;
    const int r0 = rb * 128;
    const int lane = tid & 63, wv = tid >> 6;

    // ---- load W slice into LDS once ----
    #pragma unroll
    for (int p = 0; p < 2; ++p) {
        const u16* Wp = p ? Wtlo : Wthi;
        for (int e = tid; e < 64 * (KP / 8); e += 256) {
            int col = e / (KP / 8), k8 = (e % (KP / 8)) * 8;
            int zc = (col >> 4) * NCELL + nb * 16 + (col & 15);
            *(u16x8*)&Ws[(p * 64 + col) * KL + k8] = *(const u16x8*)&Wp[(size_t)zc * KP + k8];
        }
    }
    __syncthreads();

    const int cell = nb * 16 + (lane & 15);
    const float bi = bias[cell], bj = bias[NCELL + cell];
    const float bf_ = bias[2 * NCELL + cell], bo = bias[3 * NCELL + cell];

    const int akof = (lane >> 4) * 8;
    const size_t arow = (size_t)(r0 + wv * 32 + (lane & 15));
    const size_t aoff0 = arow * KP + akof;          // m = 0
    const size_t aoff1 = aoff0 + (size_t)16 * KP;   // m = 1

    float ct[2][4] = {};   // persistent cell state in registers

    for (int t = 0; t < SEQ; ++t) {
        const u16* Hh = (t & 1) ? H1hi : H0hi;
        const u16* Hl = (t & 1) ? H1lo : H0lo;
        u16* Nh = (t & 1) ? H0hi : H1hi;
        u16* Nl = (t & 1) ? H0lo : H1lo;

        f32x4 acc[2][4] = {};   // [m][gate]
        s16x8 fr[3][4];         // A triple buffer: [buf][m0hi,m0lo,m1hi,m1lo]

#define ALOAD(f, ch) do { \
        f[0] = *(const s16x8*)(Hh + aoff0 + (ch) * 32); \
        f[1] = *(const s16x8*)(Hl + aoff0 + (ch) * 32); \
        f[2] = *(const s16x8*)(Hh + aoff1 + (ch) * 32); \
        f[3] = *(const s16x8*)(Hl + aoff1 + (ch) * 32); } while (0)
#define CCOMP(f, ch) do { \
        s16x8 bh[4], bl[4]; \
        _Pragma("unroll") \
        for (int n = 0; n < 4; ++n) { \
            bh[n] = *(const s16x8*)&Ws[(n * 16 + (lane & 15)) * KL + (ch) * 32 + akof]; \
            bl[n] = *(const s16x8*)&Ws[(64 + n * 16 + (lane & 15)) * KL + (ch) * 32 + akof]; \
        } \
        _Pragma("unroll") \
        for (int m = 0; m < 2; ++m) { \
            _Pragma("unroll") \
            for (int n = 0; n < 4; ++n) { \
                acc[m][n] = __builtin_amdgcn_mfma_f32_16x16x32_bf16(f[2*m],   bh[n], acc[m][n], 0, 0, 0); \
                acc[m][n] = __builtin_amdgcn_mfma_f32_16x16x32_bf16(f[2*m],   bl[n], acc[m][n], 0, 0, 0); \
                acc[m][n] = __builtin_amdgcn_mfma_f32_16x16x32_bf16(f[2*m+1], bh[n], acc[m][n], 0, 0, 0); \
            } \
        } } while (0)

        ALOAD(fr[0], 0); ALOAD(fr[1], 1);
        #pragma unroll
        for (int ch = 0; ch < NCH; ++ch) {
            if (ch + 2 < NCH) ALOAD(fr[(ch + 2) % 3], ch + 2);
            CCOMP(fr[ch % 3], ch);
        }
#undef ALOAD
#undef CCOMP

        // Fused gate epilogue; c stays in registers. TF gate order: i, j, f, o.
        #pragma unroll
        for (int m = 0; m < 2; ++m) {
            #pragma unroll
            for (int r = 0; r < 4; ++r) {
                int row = r0 + wv * 32 + m * 16 + (lane >> 4) * 4 + r;
                float zi = acc[m][0][r] + bi;
                float zj = acc[m][1][r] + bj;
                float zf = acc[m][2][r] + bf_;
                float zo = acc[m][3][r] + bo;
                float cn = ct[m][r] * sigm(zf + 1.0f) + sigm(zi) * ftanh(zj);
                ct[m][r] = cn;
                float h = ftanh(cn) * sigm(zo);
                u16 hh = f2b(h);
                u16 hl = f2b(h - b2f(hh));
                size_t hx = (size_t)row * KP + cell;
                Nh[hx] = hh; Nl[hx] = hl;
                if (t == SEQ - 1) hf32[(size_t)row * NCELL + cell] = h;
            }
        }
        // Stage next step's x-slice into the next A planes.
        if (t + 1 < SEQ && nb < NFEAT && tid < 128) {
            int row = r0 + tid;
            float v = X[(size_t)row * (SEQ * NFEAT) + (t + 1) * NFEAT + nb];
            u16 vh = f2b(v), vl = f2b(v - b2f(vh));
            size_t hx = (size_t)row * KP + NCELL + nb;
            Nh[hx] = vh; Nl[hx] = vl;
        }

        // ---- grid barrier (device-scope) ----
        __syncthreads();
        if (tid == 0) {
            __threadfence();   // release: drain this WG's stores to device scope
            int n = __hip_atomic_fetch_add(bar_cnt, 1, __ATOMIC_RELAXED, __HIP_MEMORY_SCOPE_AGENT);
            if (n == NWG - 1) {
                __hip_atomic_store(bar_cnt, 0, __ATOMIC_RELAXED, __HIP_MEMORY_SCOPE_AGENT);
                __hip_atomic_store(bar_epoch, t + 1, __ATOMIC_RELEASE, __HIP_MEMORY_SCOPE_AGENT);
            } else {
                int spins = 0;
                while (__hip_atomic_load(bar_epoch, __ATOMIC_RELAXED, __HIP_MEMORY_SCOPE_AGENT) <= t) {
                    __builtin_amdgcn_s_sleep(2);
                    if (++spins > 10000000) break;   // bail out instead of hanging
                }
            }
        }
        __syncthreads();
        __threadfence();   // acquire: invalidate stale L1/L2 lines before next step's reads
    }
}

// ---------- fp32 tail GEMM: C = act(A @ Wm + bias), tile 64x64 ----------
template <int ACT>
__global__ __launch_bounds__(256) void gemm64(
    const float* __restrict__ A, const float* __restrict__ Wm,
    const float* __restrict__ bias, float* __restrict__ out,
    int M, int N, int K)
{
    __shared__ float Asf[32][65];
    __shared__ float Bsf[32][65];
    const int c0 = blockIdx.x * 64;
    const int r0 = blockIdx.y * 64;
    const int tid = (int)threadIdx.x;
    const int tx = tid & 15, ty = tid >> 4;

    float acc[4][4];
    #pragma unroll
    for (int r = 0; r < 4; ++r) { acc[r][0]=0.f; acc[r][1]=0.f; acc[r][2]=0.f; acc[r][3]=0.f; }

    for (int k0 = 0; k0 < K; k0 += 32) {
        #pragma unroll
        for (int i = 0; i < 8; ++i) {
            int e = tid + 256 * i;
            int row = e >> 5, kk = e & 31;
            Asf[kk][row] = A[(size_t)(r0 + row) * K + k0 + kk];
        }
        #pragma unroll
        for (int i = 0; i < 8; ++i) {
            int e = tid + 256 * i;
            int kk = e >> 6, cl = e & 63;
            Bsf[kk][cl] = Wm[(size_t)(k0 + kk) * N + c0 + cl];
        }
        __syncthreads();
        #pragma unroll
        for (int kk = 0; kk < 32; ++kk) {
            float b0 = Bsf[kk][tx*4], b1 = Bsf[kk][tx*4+1], b2 = Bsf[kk][tx*4+2], b3 = Bsf[kk][tx*4+3];
            #pragma unroll
            for (int r = 0; r < 4; ++r) {
                float a = Asf[kk][ty*4 + r];
                acc[r][0] = fmaf(a, b0, acc[r][0]);
                acc[r][1] = fmaf(a, b1, acc[r][1]);
                acc[r][2] = fmaf(a, b2, acc[r][2]);
                acc[r][3] = fmaf(a, b3, acc[r][3]);
            }
        }
        __syncthreads();
    }
    #pragma unroll
    for (int r = 0; r < 4; ++r) {
        int gr = r0 + ty * 4 + r;
        #pragma unroll
        for (int j = 0; j < 4; ++j) {
            int gc = c0 + tx * 4 + j;
            float v = acc[r][j] + bias[gc];
            if (ACT) v = fmaxf(v, 0.f);
            out[(size_t)gr * N + gc] = v;
        }
    }
}

extern "C" void kernel_launch(void* const* d_in, const int* in_sizes, int n_in,
                              void* d_out, int out_size, void* d_ws, size_t ws_size,
                              hipStream_t stream)
{
    const float* X  = (const float*)d_in[0];
    const float* Wl = (const float*)d_in[1];
    const float* bl = (const float*)d_in[2];
    const float* Wd = (const float*)d_in[3];
    const float* bd = (const float*)d_in[4];
    const float* Wp = (const float*)d_in[5];
    const float* bp = (const float*)d_in[6];
    float* out = (float*)d_out;

    // ws layout
    char* p = (char*)d_ws;
    int* bar      = (int*)p; p += 256;                               // bar[0]=cnt, bar[32]=epoch
    float* hf32   = (float*)p; p += (size_t)BATCH * NCELL * 4;       // 2 MB
    float* dense  = (float*)p; p += (size_t)BATCH * DENSE_N * 4;     // 8 MB
    u16* Wthi = (u16*)p; p += (size_t)ZC * KP * 2;                   // 2.23 MB
    u16* Wtlo = (u16*)p; p += (size_t)ZC * KP * 2;
    u16* H0hi = (u16*)p; p += (size_t)BATCH * KP * 2;                // 1.09 MB
    u16* H0lo = (u16*)p; p += (size_t)BATCH * KP * 2;
    u16* H1hi = (u16*)p; p += (size_t)BATCH * KP * 2;
    u16* H1lo = (u16*)p; p += (size_t)BATCH * KP * 2;

    (void)hipMemsetAsync(bar, 0, 256, stream);
    prep_w<<<(ZC * KP) / 256, 256, 0, stream>>>(Wl, Wthi, Wtlo);
    prep_h<<<(BATCH * KP) / 256, 256, 0, stream>>>(X, H0hi, H0lo, H1hi, H1lo);

    const int lds_bytes = 2 * 64 * KL * 2;   // 141312
    (void)hipFuncSetAttribute((const void*)lstm_persist,
                              hipFuncAttributeMaxDynamicSharedMemorySize, lds_bytes);
    lstm_persist<<<NWG, 256, lds_bytes, stream>>>(H0hi, H0lo, H1hi, H1lo,
                                                  Wthi, Wtlo, bl, X, hf32,
                                                  &bar[0], &bar[32]);

    dim3 blk(256);
    gemm64<1><<<dim3(DENSE_N / 64, BATCH / 64), blk, 0, stream>>>(hf32, Wd, bd, dense, BATCH, DENSE_N, NCELL);
    gemm64<0><<<dim3(PRED_N / 64, BATCH / 64), blk, 0, stream>>>(dense, Wp, bp, out, BATCH, PRED_N, DENSE_N);
}

// Round 6
// 18380.750 us; speedup vs baseline: 1.3531x; 1.3531x over previous
//
#include <hip/hip_runtime.h>

#define BATCH 1024
#define SEQ 512
#define NFEAT 24
#define NCELL 512
#define ZC 2048      // 4*NCELL
#define KP 544       // reordered K: [h(512) | x(24) | pad(8)]
#define HSTRIDE 576  // H row stride in u16 (1152 B = 9 cachelines, group-aligned)
#define NCH 17       // K chunks of 32
#define KL 552       // LDS k-stride in u16
#define DENSE_N 2048
#define PRED_N 576
#define NWG 256
#define NGRP 8       // row groups (128 rows each), one barrier per group
#define GWG 32       // WGs per group

typedef unsigned short u16;
typedef unsigned short u16x8 __attribute__((ext_vector_type(8)));
typedef short s16x8 __attribute__((ext_vector_type(8)));
typedef float f32x4 __attribute__((ext_vector_type(4)));

__device__ __forceinline__ float sigm(float x) { return 1.f / (1.f + __expf(-x)); }
__device__ __forceinline__ float ftanh(float x) {
    float t = __expf(-2.f * fabsf(x));
    float r = (1.f - t) / (1.f + t);
    return copysignf(r, x);
}
__device__ __forceinline__ u16 f2b(float v) {           // f32 -> bf16 RTNE
    unsigned int x = __float_as_uint(v);
    unsigned int r = (x + 0x7fffu + ((x >> 16) & 1u)) >> 16;
    return (u16)r;
}
__device__ __forceinline__ float b2f(u16 u) { return __uint_as_float(((unsigned int)u) << 16); }

// ---------- prep: W -> transposed, K-reordered, split hi/lo ----------
__global__ __launch_bounds__(256) void prep_w(const float* __restrict__ W,
                                              u16* __restrict__ Whi, u16* __restrict__ Wlo) {
    int o = blockIdx.x * 256 + threadIdx.x;            // over ZC*KP
    if (o >= ZC * KP) return;
    int n = o / KP, k = o % KP;
    float v = 0.f;
    if (k < NCELL)              v = W[(size_t)(NFEAT + k) * ZC + n];   // h rows
    else if (k < NCELL + NFEAT) v = W[(size_t)(k - NCELL) * ZC + n];   // x rows
    u16 hi = f2b(v);
    u16 lo = f2b(v - b2f(hi));
    Whi[o] = hi; Wlo[o] = lo;
}

// ---------- prep: H0 = [h=0 | x_0 | 0], H1 = 0 (HSTRIDE rows) ----------
__global__ __launch_bounds__(256) void prep_h(const float* __restrict__ X,
                                              u16* __restrict__ H0hi, u16* __restrict__ H0lo,
                                              u16* __restrict__ H1hi, u16* __restrict__ H1lo) {
    int o = blockIdx.x * 256 + threadIdx.x;            // over BATCH*KP
    if (o >= BATCH * KP) return;
    int row = o / KP, k = o % KP;
    u16 hi = 0, lo = 0;
    if (k >= NCELL && k < NCELL + NFEAT) {
        float v = X[(size_t)row * (SEQ * NFEAT) + (k - NCELL)];  // t = 0
        hi = f2b(v); lo = f2b(v - b2f(hi));
    }
    size_t hx = (size_t)row * HSTRIDE + k;
    H0hi[hx] = hi; H0lo[hx] = lo;
    H1hi[hx] = 0;  H1lo[hx] = 0;
}

// ---------- persistent LSTM: all 512 steps, row-group-local barriers ----------
// bid: rb = bid & 7 (row group -> same XCD under round-robin), nb = bid >> 3.
// WG tile = 128 rows x 64 z-cols (16 cells x 4 gates). W slice in LDS; c in regs.
__global__ __launch_bounds__(256, 1) void lstm_persist(
    u16* __restrict__ H0hi, u16* __restrict__ H0lo,
    u16* __restrict__ H1hi, u16* __restrict__ H1lo,
    const u16* __restrict__ Wthi, const u16* __restrict__ Wtlo,  // [ZC][KP]
    const float* __restrict__ bias,                              // [ZC]
    const float* __restrict__ X,                                 // [BATCH][SEQ][NFEAT]
    float* __restrict__ hf32,                                    // [BATCH][NCELL]
    int* __restrict__ bar)                                       // 8 x 64 ints
{
    extern __shared__ u16 Ws[];   // [2 planes][64 cols][KL]

    const int tid = (int)threadIdx.x;
    const int bid = (int)blockIdx.x;
    const int rb = bid & 7, nb = bid >> 3;
    const int r0 = rb * 128;
    const int lane = tid & 63, wv = tid >> 6;
    int* __restrict__ bcnt   = bar + rb * 64;        // group counter line
    int* __restrict__ bepoch = bar + rb * 64 + 32;   // group epoch line

    // ---- load W slice into LDS once ----
    #pragma unroll
    for (int p = 0; p < 2; ++p) {
        const u16* Wp = p ? Wtlo : Wthi;
        for (int e = tid; e < 64 * (KP / 8); e += 256) {
            int col = e / (KP / 8), k8 = (e % (KP / 8)) * 8;
            int zc = (col >> 4) * NCELL + nb * 16 + (col & 15);
            *(u16x8*)&Ws[(p * 64 + col) * KL + k8] = *(const u16x8*)&Wp[(size_t)zc * KP + k8];
        }
    }
    __syncthreads();

    const int cell = nb * 16 + (lane & 15);
    const float bi = bias[cell], bj = bias[NCELL + cell];
    const float bf_ = bias[2 * NCELL + cell], bo = bias[3 * NCELL + cell];

    const int akof = (lane >> 4) * 8;
    const size_t arow = (size_t)(r0 + wv * 32 + (lane & 15));
    const size_t aoff0 = arow * HSTRIDE + akof;          // m = 0
    const size_t aoff1 = aoff0 + (size_t)16 * HSTRIDE;   // m = 1

    float ct[2][4] = {};   // persistent cell state in registers

    for (int t = 0; t < SEQ; ++t) {
        const u16* Hh = (t & 1) ? H1hi : H0hi;
        const u16* Hl = (t & 1) ? H1lo : H0lo;
        u16* Nh = (t & 1) ? H0hi : H1hi;
        u16* Nl = (t & 1) ? H0lo : H1lo;

        f32x4 acc[2][4] = {};   // [m][gate]
        s16x8 fr[3][4];         // A triple buffer: [buf][m0hi,m0lo,m1hi,m1lo]

#define ALOAD(f, ch) do { \
        f[0] = *(const s16x8*)(Hh + aoff0 + (ch) * 32); \
        f[1] = *(const s16x8*)(Hl + aoff0 + (ch) * 32); \
        f[2] = *(const s16x8*)(Hh + aoff1 + (ch) * 32); \
        f[3] = *(const s16x8*)(Hl + aoff1 + (ch) * 32); } while (0)
#define CCOMP(f, ch) do { \
        s16x8 bh[4], bl[4]; \
        _Pragma("unroll") \
        for (int n = 0; n < 4; ++n) { \
            bh[n] = *(const s16x8*)&Ws[(n * 16 + (lane & 15)) * KL + (ch) * 32 + akof]; \
            bl[n] = *(const s16x8*)&Ws[(64 + n * 16 + (lane & 15)) * KL + (ch) * 32 + akof]; \
        } \
        _Pragma("unroll") \
        for (int m = 0; m < 2; ++m) { \
            _Pragma("unroll") \
            for (int n = 0; n < 4; ++n) { \
                acc[m][n] = __builtin_amdgcn_mfma_f32_16x16x32_bf16(f[2*m],   bh[n], acc[m][n], 0, 0, 0); \
                acc[m][n] = __builtin_amdgcn_mfma_f32_16x16x32_bf16(f[2*m],   bl[n], acc[m][n], 0, 0, 0); \
                acc[m][n] = __builtin_amdgcn_mfma_f32_16x16x32_bf16(f[2*m+1], bh[n], acc[m][n], 0, 0, 0); \
            } \
        } } while (0)

        ALOAD(fr[0], 0); ALOAD(fr[1], 1);
        #pragma unroll
        for (int ch = 0; ch < NCH; ++ch) {
            if (ch + 2 < NCH) ALOAD(fr[(ch + 2) % 3], ch + 2);
            CCOMP(fr[ch % 3], ch);
        }
#undef ALOAD
#undef CCOMP

        // Fused gate epilogue; c stays in registers. TF gate order: i, j, f, o.
        #pragma unroll
        for (int m = 0; m < 2; ++m) {
            #pragma unroll
            for (int r = 0; r < 4; ++r) {
                int row = r0 + wv * 32 + m * 16 + (lane >> 4) * 4 + r;
                float zi = acc[m][0][r] + bi;
                float zj = acc[m][1][r] + bj;
                float zf = acc[m][2][r] + bf_;
                float zo = acc[m][3][r] + bo;
                float cn = ct[m][r] * sigm(zf + 1.0f) + sigm(zi) * ftanh(zj);
                ct[m][r] = cn;
                float h = ftanh(cn) * sigm(zo);
                u16 hh = f2b(h);
                u16 hl = f2b(h - b2f(hh));
                size_t hx = (size_t)row * HSTRIDE + cell;
                Nh[hx] = hh; Nl[hx] = hl;
                if (t == SEQ - 1) hf32[(size_t)row * NCELL + cell] = h;
            }
        }
        // Stage next step's x-slice into the next A planes.
        if (t + 1 < SEQ && nb < NFEAT && tid < 128) {
            int row = r0 + tid;
            float v = X[(size_t)row * (SEQ * NFEAT) + (t + 1) * NFEAT + nb];
            u16 vh = f2b(v), vl = f2b(v - b2f(vh));
            size_t hx = (size_t)row * HSTRIDE + NCELL + nb;
            Nh[hx] = vh; Nl[hx] = vl;
        }

        // ---- row-group barrier (32 WGs, own cacheline, agent scope) ----
        __syncthreads();
        if (tid == 0) {
            __threadfence();   // release: publish this WG's H stores
            int n = __hip_atomic_fetch_add(bcnt, 1, __ATOMIC_RELAXED, __HIP_MEMORY_SCOPE_AGENT);
            if (n == GWG - 1) {
                __hip_atomic_store(bcnt, 0, __ATOMIC_RELAXED, __HIP_MEMORY_SCOPE_AGENT);
                __hip_atomic_store(bepoch, t + 1, __ATOMIC_RELEASE, __HIP_MEMORY_SCOPE_AGENT);
            } else {
                int spins = 0;
                while (__hip_atomic_load(bepoch, __ATOMIC_RELAXED, __HIP_MEMORY_SCOPE_AGENT) <= t) {
                    __builtin_amdgcn_s_sleep(4);
                    if (++spins > 20000000) break;   // bail out instead of hanging
                }
            }
        }
        __syncthreads();
        __threadfence();   // acquire: drop stale lines before next step's reads
    }
}

// ---------- fp32 tail GEMM: C = act(A @ Wm + bias), tile 64x64 ----------
template <int ACT>
__global__ __launch_bounds__(256) void gemm64(
    const float* __restrict__ A, const float* __restrict__ Wm,
    const float* __restrict__ bias, float* __restrict__ out,
    int M, int N, int K)
{
    __shared__ float Asf[32][65];
    __shared__ float Bsf[32][65];
    const int c0 = blockIdx.x * 64;
    const int r0 = blockIdx.y * 64;
    const int tid = (int)threadIdx.x;
    const int tx = tid & 15, ty = tid >> 4;

    float acc[4][4];
    #pragma unroll
    for (int r = 0; r < 4; ++r) { acc[r][0]=0.f; acc[r][1]=0.f; acc[r][2]=0.f; acc[r][3]=0.f; }

    for (int k0 = 0; k0 < K; k0 += 32) {
        #pragma unroll
        for (int i = 0; i < 8; ++i) {
            int e = tid + 256 * i;
            int row = e >> 5, kk = e & 31;
            Asf[kk][row] = A[(size_t)(r0 + row) * K + k0 + kk];
        }
        #pragma unroll
        for (int i = 0; i < 8; ++i) {
            int e = tid + 256 * i;
            int kk = e >> 6, cl = e & 63;
            Bsf[kk][cl] = Wm[(size_t)(k0 + kk) * N + c0 + cl];
        }
        __syncthreads();
        #pragma unroll
        for (int kk = 0; kk < 32; ++kk) {
            float b0 = Bsf[kk][tx*4], b1 = Bsf[kk][tx*4+1], b2 = Bsf[kk][tx*4+2], b3 = Bsf[kk][tx*4+3];
            #pragma unroll
            for (int r = 0; r < 4; ++r) {
                float a = Asf[kk][ty*4 + r];
                acc[r][0] = fmaf(a, b0, acc[r][0]);
                acc[r][1] = fmaf(a, b1, acc[r][1]);
                acc[r][2] = fmaf(a, b2, acc[r][2]);
                acc[r][3] = fmaf(a, b3, acc[r][3]);
            }
        }
        __syncthreads();
    }
    #pragma unroll
    for (int r = 0; r < 4; ++r) {
        int gr = r0 + ty * 4 + r;
        #pragma unroll
        for (int j = 0; j < 4; ++j) {
            int gc = c0 + tx * 4 + j;
            float v = acc[r][j] + bias[gc];
            if (ACT) v = fmaxf(v, 0.f);
            out[(size_t)gr * N + gc] = v;
        }
    }
}

extern "C" void kernel_launch(void* const* d_in, const int* in_sizes, int n_in,
                              void* d_out, int out_size, void* d_ws, size_t ws_size,
                              hipStream_t stream)
{
    const float* X  = (const float*)d_in[0];
    const float* Wl = (const float*)d_in[1];
    const float* bl = (const float*)d_in[2];
    const float* Wd = (const float*)d_in[3];
    const float* bd = (const float*)d_in[4];
    const float* Wp = (const float*)d_in[5];
    const float* bp = (const float*)d_in[6];
    float* out = (float*)d_out;

    // ws layout
    char* p = (char*)d_ws;
    int* bar      = (int*)p; p += 4096;                              // 8 groups x 256 B
    float* hf32   = (float*)p; p += (size_t)BATCH * NCELL * 4;       // 2 MB
    float* dense  = (float*)p; p += (size_t)BATCH * DENSE_N * 4;     // 8 MB
    u16* Wthi = (u16*)p; p += (size_t)ZC * KP * 2;                   // 2.23 MB
    u16* Wtlo = (u16*)p; p += (size_t)ZC * KP * 2;
    u16* H0hi = (u16*)p; p += (size_t)BATCH * HSTRIDE * 2;           // 1.125 MB
    u16* H0lo = (u16*)p; p += (size_t)BATCH * HSTRIDE * 2;
    u16* H1hi = (u16*)p; p += (size_t)BATCH * HSTRIDE * 2;
    u16* H1lo = (u16*)p; p += (size_t)BATCH * HSTRIDE * 2;

    (void)hipMemsetAsync(bar, 0, 4096, stream);
    prep_w<<<(ZC * KP) / 256, 256, 0, stream>>>(Wl, Wthi, Wtlo);
    prep_h<<<(BATCH * KP) / 256, 256, 0, stream>>>(X, H0hi, H0lo, H1hi, H1lo);

    const int lds_bytes = 2 * 64 * KL * 2;   // 141312
    (void)hipFuncSetAttribute((const void*)lstm_persist,
                              hipFuncAttributeMaxDynamicSharedMemorySize, lds_bytes);
    lstm_persist<<<NWG, 256, lds_bytes, stream>>>(H0hi, H0lo, H1hi, H1lo,
                                                  Wthi, Wtlo, bl, X, hf32, bar);

    dim3 blk(256);
    gemm64<1><<<dim3(DENSE_N / 64, BATCH / 64), blk, 0, stream>>>(hf32, Wd, bd, dense, BATCH, DENSE_N, NCELL);
    gemm64<0><<<dim3(PRED_N / 64, BATCH / 64), blk, 0, stream>>>(dense, Wp, bp, out, BATCH, PRED_N, DENSE_N);
}

// Round 7
// 8377.209 us; speedup vs baseline: 2.9689x; 2.1941x over previous
//
#include <hip/hip_runtime.h>

#define BATCH 1024
#define SEQ 512
#define NFEAT 24
#define NCELL 512
#define ZC 2048      // 4*NCELL
#define KP 544       // reordered K: [h(512) | x(24) | pad(8)]
#define HSTRIDE 576  // H row stride in u32 (2304 B)
#define NCH 17       // K chunks of 32
#define KL 552       // LDS k-stride in u16
#define DENSE_N 2048
#define PRED_N 576
#define NWG 256
#define NGRP 8       // row groups (128 rows each), one barrier per group
#define GWG 32       // WGs per group

#ifndef __MEMORY_SCOPE_DEVICE
#define __MEMORY_SCOPE_DEVICE 1
#endif

typedef unsigned short u16;
typedef unsigned int u32;
typedef unsigned short u16x8 __attribute__((ext_vector_type(8)));
typedef short s16x8 __attribute__((ext_vector_type(8)));
typedef u32 u32x4 __attribute__((ext_vector_type(4)));
typedef float f32x4 __attribute__((ext_vector_type(4)));

__device__ __forceinline__ float sigm(float x) { return 1.f / (1.f + __expf(-x)); }
__device__ __forceinline__ float ftanh(float x) {
    float t = __expf(-2.f * fabsf(x));
    float r = (1.f - t) / (1.f + t);
    return copysignf(r, x);
}
__device__ __forceinline__ u16 f2b(float v) {           // f32 -> bf16 RTNE
    unsigned int x = __float_as_uint(v);
    unsigned int r = (x + 0x7fffu + ((x >> 16) & 1u)) >> 16;
    return (u16)r;
}
__device__ __forceinline__ float b2f(u16 u) { return __uint_as_float(((unsigned int)u) << 16); }

// unpack 8 packed cells (lo16=hi-plane bf16, hi16=lo-plane bf16) into two s16x8
__device__ __forceinline__ void unpack16(const u32x4 a, const u32x4 b, s16x8* hi, s16x8* lo) {
    u32* h = (u32*)hi; u32* l = (u32*)lo;
    h[0] = __builtin_amdgcn_perm(a[1], a[0], 0x05040100u);
    h[1] = __builtin_amdgcn_perm(a[3], a[2], 0x05040100u);
    h[2] = __builtin_amdgcn_perm(b[1], b[0], 0x05040100u);
    h[3] = __builtin_amdgcn_perm(b[3], b[2], 0x05040100u);
    l[0] = __builtin_amdgcn_perm(a[1], a[0], 0x07060302u);
    l[1] = __builtin_amdgcn_perm(a[3], a[2], 0x07060302u);
    l[2] = __builtin_amdgcn_perm(b[1], b[0], 0x07060302u);
    l[3] = __builtin_amdgcn_perm(b[3], b[2], 0x07060302u);
}

// ---------- prep: W -> transposed, K-reordered, split hi/lo ----------
__global__ __launch_bounds__(256) void prep_w(const float* __restrict__ W,
                                              u16* __restrict__ Whi, u16* __restrict__ Wlo) {
    int o = blockIdx.x * 256 + threadIdx.x;            // over ZC*KP
    if (o >= ZC * KP) return;
    int n = o / KP, k = o % KP;
    float v = 0.f;
    if (k < NCELL)              v = W[(size_t)(NFEAT + k) * ZC + n];   // h rows
    else if (k < NCELL + NFEAT) v = W[(size_t)(k - NCELL) * ZC + n];   // x rows
    u16 hi = f2b(v);
    u16 lo = f2b(v - b2f(hi));
    Whi[o] = hi; Wlo[o] = lo;
}

// ---------- prep: H0 = [h=0 | x_0 | 0], H1 = 0 (packed u32) ----------
__global__ __launch_bounds__(256) void prep_h(const float* __restrict__ X,
                                              u32* __restrict__ H0, u32* __restrict__ H1) {
    int o = blockIdx.x * 256 + threadIdx.x;            // over BATCH*KP
    if (o >= BATCH * KP) return;
    int row = o / KP, k = o % KP;
    u32 pk = 0;
    if (k >= NCELL && k < NCELL + NFEAT) {
        float v = X[(size_t)row * (SEQ * NFEAT) + (k - NCELL)];  // t = 0
        u16 hi = f2b(v), lo = f2b(v - b2f(hi));
        pk = (u32)hi | ((u32)lo << 16);
    }
    size_t hx = (size_t)row * HSTRIDE + k;
    H0[hx] = pk;
    H1[hx] = 0;
}

// ---------- persistent LSTM: all 512 steps, row-group barriers, no cache flushes ----------
// bid: rb = bid & 7 (row group -> one XCD under round-robin), nb = bid >> 3.
// WG tile = 128 rows x 64 z-cols. W slice in LDS; c in regs; H packed u32,
// written via agent-scope (write-through) atomic stores.
__global__ __launch_bounds__(256, 1) void lstm_persist(
    u32* __restrict__ H0, u32* __restrict__ H1,
    const u16* __restrict__ Wthi, const u16* __restrict__ Wtlo,  // [ZC][KP]
    const float* __restrict__ bias,                              // [ZC]
    const float* __restrict__ X,                                 // [BATCH][SEQ][NFEAT]
    float* __restrict__ hf32,                                    // [BATCH][NCELL]
    int* __restrict__ bar)                                       // 8 x 64 ints
{
    extern __shared__ u16 Ws[];   // [2 planes][64 cols][KL]

    const int tid = (int)threadIdx.x;
    const int bid = (int)blockIdx.x;
    const int rb = bid & 7, nb = bid >> 3;
    const int r0 = rb * 128;
    const int lane = tid & 63, wv = tid >> 6;
    int* __restrict__ bcnt   = bar + rb * 64;        // group counter line
    int* __restrict__ bepoch = bar + rb * 64 + 32;   // group epoch line

    // ---- load W slice into LDS once ----
    #pragma unroll
    for (int p = 0; p < 2; ++p) {
        const u16* Wp = p ? Wtlo : Wthi;
        for (int e = tid; e < 64 * (KP / 8); e += 256) {
            int col = e / (KP / 8), k8 = (e % (KP / 8)) * 8;
            int zc = (col >> 4) * NCELL + nb * 16 + (col & 15);
            *(u16x8*)&Ws[(p * 64 + col) * KL + k8] = *(const u16x8*)&Wp[(size_t)zc * KP + k8];
        }
    }
    __syncthreads();

    const int cell = nb * 16 + (lane & 15);
    const float bi = bias[cell], bj = bias[NCELL + cell];
    const float bf_ = bias[2 * NCELL + cell], bo = bias[3 * NCELL + cell];

    const int akof = (lane >> 4) * 8;
    const size_t arow = (size_t)(r0 + wv * 32 + (lane & 15));
    const size_t aoff0 = arow * HSTRIDE + akof;          // m = 0 (u32 units)
    const size_t aoff1 = aoff0 + (size_t)16 * HSTRIDE;   // m = 1

    float ct[2][4] = {};   // persistent cell state in registers

    for (int t = 0; t < SEQ; ++t) {
        const u32* Hc = (t & 1) ? H1 : H0;
        u32*       Np = (t & 1) ? H0 : H1;

        f32x4 acc[2][4] = {};   // [m][gate]
        u32x4 fr[3][4];         // A triple buffer (packed)

#define ALOAD(f, ch) do { \
        f[0] = *(const u32x4*)(Hc + aoff0 + (ch) * 32); \
        f[1] = *(const u32x4*)(Hc + aoff0 + (ch) * 32 + 4); \
        f[2] = *(const u32x4*)(Hc + aoff1 + (ch) * 32); \
        f[3] = *(const u32x4*)(Hc + aoff1 + (ch) * 32 + 4); } while (0)
#define CCOMP(f, ch) do { \
        s16x8 ah0, al0, ah1, al1; \
        unpack16(f[0], f[1], &ah0, &al0); \
        unpack16(f[2], f[3], &ah1, &al1); \
        s16x8 bh[4], bl[4]; \
        _Pragma("unroll") \
        for (int n = 0; n < 4; ++n) { \
            bh[n] = *(const s16x8*)&Ws[(n * 16 + (lane & 15)) * KL + (ch) * 32 + akof]; \
            bl[n] = *(const s16x8*)&Ws[(64 + n * 16 + (lane & 15)) * KL + (ch) * 32 + akof]; \
        } \
        _Pragma("unroll") \
        for (int n = 0; n < 4; ++n) { \
            acc[0][n] = __builtin_amdgcn_mfma_f32_16x16x32_bf16(ah0, bh[n], acc[0][n], 0, 0, 0); \
            acc[0][n] = __builtin_amdgcn_mfma_f32_16x16x32_bf16(ah0, bl[n], acc[0][n], 0, 0, 0); \
            acc[0][n] = __builtin_amdgcn_mfma_f32_16x16x32_bf16(al0, bh[n], acc[0][n], 0, 0, 0); \
            acc[1][n] = __builtin_amdgcn_mfma_f32_16x16x32_bf16(ah1, bh[n], acc[1][n], 0, 0, 0); \
            acc[1][n] = __builtin_amdgcn_mfma_f32_16x16x32_bf16(ah1, bl[n], acc[1][n], 0, 0, 0); \
            acc[1][n] = __builtin_amdgcn_mfma_f32_16x16x32_bf16(al1, bh[n], acc[1][n], 0, 0, 0); \
        } } while (0)

        ALOAD(fr[0], 0); ALOAD(fr[1], 1);
        #pragma unroll
        for (int ch = 0; ch < NCH; ++ch) {
            if (ch + 2 < NCH) ALOAD(fr[(ch + 2) % 3], ch + 2);
            CCOMP(fr[ch % 3], ch);
        }
#undef ALOAD
#undef CCOMP

        // Fused gate epilogue; c in registers. TF gate order: i, j, f, o.
        // H stores: agent-scope relaxed (write-through) -> no wbl2 needed.
        #pragma unroll
        for (int m = 0; m < 2; ++m) {
            #pragma unroll
            for (int r = 0; r < 4; ++r) {
                int row = r0 + wv * 32 + m * 16 + (lane >> 4) * 4 + r;
                float zi = acc[m][0][r] + bi;
                float zj = acc[m][1][r] + bj;
                float zf = acc[m][2][r] + bf_;
                float zo = acc[m][3][r] + bo;
                float cn = ct[m][r] * sigm(zf + 1.0f) + sigm(zi) * ftanh(zj);
                ct[m][r] = cn;
                float h = ftanh(cn) * sigm(zo);
                u16 hh = f2b(h);
                u16 hl = f2b(h - b2f(hh));
                u32 pk = (u32)hh | ((u32)hl << 16);
                __hip_atomic_store(&Np[(size_t)row * HSTRIDE + cell], pk,
                                   __ATOMIC_RELAXED, __HIP_MEMORY_SCOPE_AGENT);
                if (t == SEQ - 1) hf32[(size_t)row * NCELL + cell] = h;
            }
        }
        // Stage next step's x-slice into the next A plane.
        if (t + 1 < SEQ && nb < NFEAT && tid < 128) {
            int row = r0 + tid;
            float v = X[(size_t)row * (SEQ * NFEAT) + (t + 1) * NFEAT + nb];
            u16 vh = f2b(v), vl = f2b(v - b2f(vh));
            u32 pk = (u32)vh | ((u32)vl << 16);
            __hip_atomic_store(&Np[(size_t)row * HSTRIDE + NCELL + nb], pk,
                               __ATOMIC_RELAXED, __HIP_MEMORY_SCOPE_AGENT);
        }

        // ---- row-group barrier: counter only, one acquire-inv per WG ----
        __syncthreads();   // drains vmcnt: write-through stores now device-visible
        if (tid == 0) {
            int n = __hip_atomic_fetch_add(bcnt, 1, __ATOMIC_RELAXED, __HIP_MEMORY_SCOPE_AGENT);
            if (n == GWG - 1) {
                __hip_atomic_store(bcnt, 0, __ATOMIC_RELAXED, __HIP_MEMORY_SCOPE_AGENT);
                __hip_atomic_store(bepoch, t + 1, __ATOMIC_RELEASE, __HIP_MEMORY_SCOPE_AGENT);
            } else {
                int spins = 0;
                while (__hip_atomic_load(bepoch, __ATOMIC_RELAXED, __HIP_MEMORY_SCOPE_AGENT) <= t) {
                    __builtin_amdgcn_s_sleep(4);
                    if (++spins > 20000000) break;   // bail out instead of hanging
                }
            }
            // acquire: drop stale L1/L2 lines once per WG
            __scoped_atomic_thread_fence(__ATOMIC_ACQUIRE, __MEMORY_SCOPE_DEVICE);
        }
        __syncthreads();
    }
}

// ---------- fp32 tail GEMM: C = act(A @ Wm + bias), tile 64x64 ----------
template <int ACT>
__global__ __launch_bounds__(256) void gemm64(
    const float* __restrict__ A, const float* __restrict__ Wm,
    const float* __restrict__ bias, float* __restrict__ out,
    int M, int N, int K)
{
    __shared__ float Asf[32][65];
    __shared__ float Bsf[32][65];
    const int c0 = blockIdx.x * 64;
    const int r0 = blockIdx.y * 64;
    const int tid = (int)threadIdx.x;
    const int tx = tid & 15, ty = tid >> 4;

    float acc[4][4];
    #pragma unroll
    for (int r = 0; r < 4; ++r) { acc[r][0]=0.f; acc[r][1]=0.f; acc[r][2]=0.f; acc[r][3]=0.f; }

    for (int k0 = 0; k0 < K; k0 += 32) {
        #pragma unroll
        for (int i = 0; i < 8; ++i) {
            int e = tid + 256 * i;
            int row = e >> 5, kk = e & 31;
            Asf[kk][row] = A[(size_t)(r0 + row) * K + k0 + kk];
        }
        #pragma unroll
        for (int i = 0; i < 8; ++i) {
            int e = tid + 256 * i;
            int kk = e >> 6, cl = e & 63;
            Bsf[kk][cl] = Wm[(size_t)(k0 + kk) * N + c0 + cl];
        }
        __syncthreads();
        #pragma unroll
        for (int kk = 0; kk < 32; ++kk) {
            float b0 = Bsf[kk][tx*4], b1 = Bsf[kk][tx*4+1], b2 = Bsf[kk][tx*4+2], b3 = Bsf[kk][tx*4+3];
            #pragma unroll
            for (int r = 0; r < 4; ++r) {
                float a = Asf[kk][ty*4 + r];
                acc[r][0] = fmaf(a, b0, acc[r][0]);
                acc[r][1] = fmaf(a, b1, acc[r][1]);
                acc[r][2] = fmaf(a, b2, acc[r][2]);
                acc[r][3] = fmaf(a, b3, acc[r][3]);
            }
        }
        __syncthreads();
    }
    #pragma unroll
    for (int r = 0; r < 4; ++r) {
        int gr = r0 + ty * 4 + r;
        #pragma unroll
        for (int j = 0; j < 4; ++j) {
            int gc = c0 + tx * 4 + j;
            float v = acc[r][j] + bias[gc];
            if (ACT) v = fmaxf(v, 0.f);
            out[(size_t)gr * N + gc] = v;
        }
    }
}

extern "C" void kernel_launch(void* const* d_in, const int* in_sizes, int n_in,
                              void* d_out, int out_size, void* d_ws, size_t ws_size,
                              hipStream_t stream)
{
    const float* X  = (const float*)d_in[0];
    const float* Wl = (const float*)d_in[1];
    const float* bl = (const float*)d_in[2];
    const float* Wd = (const float*)d_in[3];
    const float* bd = (const float*)d_in[4];
    const float* Wp = (const float*)d_in[5];
    const float* bp = (const float*)d_in[6];
    float* out = (float*)d_out;

    // ws layout
    char* p = (char*)d_ws;
    int* bar      = (int*)p; p += 4096;                              // 8 groups x 256 B
    float* hf32   = (float*)p; p += (size_t)BATCH * NCELL * 4;       // 2 MB
    float* dense  = (float*)p; p += (size_t)BATCH * DENSE_N * 4;     // 8 MB
    u16* Wthi = (u16*)p; p += (size_t)ZC * KP * 2;                   // 2.23 MB
    u16* Wtlo = (u16*)p; p += (size_t)ZC * KP * 2;
    u32* H0   = (u32*)p; p += (size_t)BATCH * HSTRIDE * 4;           // 2.25 MB
    u32* H1   = (u32*)p; p += (size_t)BATCH * HSTRIDE * 4;

    (void)hipMemsetAsync(bar, 0, 4096, stream);
    prep_w<<<(ZC * KP) / 256, 256, 0, stream>>>(Wl, Wthi, Wtlo);
    prep_h<<<(BATCH * KP) / 256, 256, 0, stream>>>(X, H0, H1);

    const int lds_bytes = 2 * 64 * KL * 2;   // 141312
    (void)hipFuncSetAttribute((const void*)lstm_persist,
                              hipFuncAttributeMaxDynamicSharedMemorySize, lds_bytes);
    lstm_persist<<<NWG, 256, lds_bytes, stream>>>(H0, H1, Wthi, Wtlo, bl, X, hf32, bar);

    dim3 blk(256);
    gemm64<1><<<dim3(DENSE_N / 64, BATCH / 64), blk, 0, stream>>>(hf32, Wd, bd, dense, BATCH, DENSE_N, NCELL);
    gemm64<0><<<dim3(PRED_N / 64, BATCH / 64), blk, 0, stream>>>(dense, Wp, bp, out, BATCH, PRED_N, DENSE_N);
}

// Round 8
// 4647.505 us; speedup vs baseline: 5.3515x; 1.8025x over previous
//
#include <hip/hip_runtime.h>

#define BATCH 1024
#define SEQ 512
#define NFEAT 24
#define NCELL 512
#define ZC 2048      // 4*NCELL
#define KP 544       // reordered K: [h(512) | x(24) | pad(8)]
#define NCH 17       // K chunks of 32
#define KL 576       // LDS k-stride in u16 (XOR-swizzled in 16B units)
#define DENSE_N 2048
#define PRED_N 576
#define NWG 256
#define NGRP 8       // row groups (128 rows each)
#define GWG 32       // WGs per group

typedef unsigned short u16;
typedef unsigned int u32;
typedef unsigned long long u64;
typedef unsigned short u16x8 __attribute__((ext_vector_type(8)));
typedef short s16x8 __attribute__((ext_vector_type(8)));
typedef u32 u32x4 __attribute__((ext_vector_type(4)));
typedef float f32x4 __attribute__((ext_vector_type(4)));

__device__ __forceinline__ float sigm(float x) { return 1.f / (1.f + __expf(-x)); }
__device__ __forceinline__ float ftanh(float x) {
    float t = __expf(-2.f * fabsf(x));
    float r = (1.f - t) / (1.f + t);
    return copysignf(r, x);
}
__device__ __forceinline__ u16 f2b(float v) {           // f32 -> bf16 RTNE
    unsigned int x = __float_as_uint(v);
    unsigned int r = (x + 0x7fffu + ((x >> 16) & 1u)) >> 16;
    return (u16)r;
}
__device__ __forceinline__ float b2f(u16 u) { return __uint_as_float(((unsigned int)u) << 16); }

// Fragment-major H layout. u64 index: (((rb*4+wv)*NCH + ch)*8 + m*4 + i)*64 + lane.
// u32 word index for element (row, k):
__device__ __forceinline__ u32 hword(int row, int k) {
    int rb = row >> 7, wv = (row >> 5) & 3, m = (row >> 4) & 1, rl = row & 15;
    int ch = k >> 5, sub = (k & 31) >> 3, i = (k & 7) >> 1, w = k & 1;
    u32 q = (u32)(((rb * 4 + wv) * NCH + ch) * 8 + m * 4 + i) * 64u + (u32)(rl + (sub << 4));
    return q * 2u + (u32)w;
}

// unpack 8 packed cells (lo16=hi-plane bf16, hi16=lo-plane bf16) into two s16x8
__device__ __forceinline__ void unpack16(const u32x4 a, const u32x4 b, s16x8* hi, s16x8* lo) {
    u32* h = (u32*)hi; u32* l = (u32*)lo;
    h[0] = __builtin_amdgcn_perm(a[1], a[0], 0x05040100u);
    h[1] = __builtin_amdgcn_perm(a[3], a[2], 0x05040100u);
    h[2] = __builtin_amdgcn_perm(b[1], b[0], 0x05040100u);
    h[3] = __builtin_amdgcn_perm(b[3], b[2], 0x05040100u);
    l[0] = __builtin_amdgcn_perm(a[1], a[0], 0x07060302u);
    l[1] = __builtin_amdgcn_perm(a[3], a[2], 0x07060302u);
    l[2] = __builtin_amdgcn_perm(b[1], b[0], 0x07060302u);
    l[3] = __builtin_amdgcn_perm(b[3], b[2], 0x07060302u);
}

// ---------- prep: W -> transposed, K-reordered, split hi/lo ----------
__global__ __launch_bounds__(256) void prep_w(const float* __restrict__ W,
                                              u16* __restrict__ Whi, u16* __restrict__ Wlo) {
    int o = blockIdx.x * 256 + threadIdx.x;            // over ZC*KP
    if (o >= ZC * KP) return;
    int n = o / KP, k = o % KP;
    float v = 0.f;
    if (k < NCELL)              v = W[(size_t)(NFEAT + k) * ZC + n];   // h rows
    else if (k < NCELL + NFEAT) v = W[(size_t)(k - NCELL) * ZC + n];   // x rows
    u16 hi = f2b(v);
    u16 lo = f2b(v - b2f(hi));
    Whi[o] = hi; Wlo[o] = lo;
}

// ---------- prep: H0 = [h=0 | x_0 | pad=0], H1 = 0 (fragment-major packed u32) ----------
__global__ __launch_bounds__(256) void prep_h(const float* __restrict__ X,
                                              u32* __restrict__ H0, u32* __restrict__ H1) {
    int o = blockIdx.x * 256 + threadIdx.x;            // over BATCH*KP
    if (o >= BATCH * KP) return;
    int row = o / KP, k = o % KP;
    u32 pk = 0;
    if (k >= NCELL && k < NCELL + NFEAT) {
        float v = X[(size_t)row * (SEQ * NFEAT) + (k - NCELL)];  // t = 0
        u16 hi = f2b(v), lo = f2b(v - b2f(hi));
        pk = (u32)hi | ((u32)lo << 16);
    }
    u32 w = hword(row, k);
    H0[w] = pk;
    H1[w] = 0;
}

// ---------- persistent LSTM: no cache maintenance; H read/written through L3 ----------
__global__ __launch_bounds__(256, 1) void lstm_persist(
    u32* __restrict__ H0, u32* __restrict__ H1,
    const u16* __restrict__ Wthi, const u16* __restrict__ Wtlo,  // [ZC][KP]
    const float* __restrict__ bias,                              // [ZC]
    const float* __restrict__ X,                                 // [BATCH][SEQ][NFEAT]
    float* __restrict__ hf32,                                    // [BATCH][NCELL]
    int* __restrict__ bar)                                       // 8 x 64 ints
{
    extern __shared__ u16 Ws[];   // [2 planes][64 cols][KL], XOR-swizzled

    const int tid = (int)threadIdx.x;
    const int bid = (int)blockIdx.x;
    const int rb = bid & 7, nb = bid >> 3;
    const int r0 = rb * 128;
    const int lane = tid & 63, wv = tid >> 6;
    int* __restrict__ bcnt   = bar + rb * 64;
    int* __restrict__ bepoch = bar + rb * 64 + 32;

    // ---- load W slice into LDS once (swizzled) ----
    #pragma unroll
    for (int p = 0; p < 2; ++p) {
        const u16* Wp = p ? Wtlo : Wthi;
        for (int e = tid; e < 64 * (KP / 8); e += 256) {
            int col = e / (KP / 8), k8 = (e % (KP / 8)) * 8;
            int zc = (col >> 4) * NCELL + nb * 16 + (col & 15);
            int so = k8 ^ ((col & 7) << 3);
            *(u16x8*)&Ws[(p * 64 + col) * KL + so] = *(const u16x8*)&Wp[(size_t)zc * KP + k8];
        }
    }
    __syncthreads();

    const int cell = nb * 16 + (lane & 15);
    const float bi = bias[cell], bj = bias[NCELL + cell];
    const float bf_ = bias[2 * NCELL + cell], bo = bias[3 * NCELL + cell];

    const int akof = (lane >> 4) * 8;                 // k sub-offset for B frags (u16)
    // A-load base (u64 units): (((rb*4+wv)*NCH + ch)*8 + m*4 + i)*64 + lane
    const u32 wbase = (u32)((rb * 4 + wv) * NCH) * 512u + (u32)lane;

    // epilogue store constants
    const int cellch = nb >> 1;
    const int cellsub = ((nb & 1) << 1) + ((lane & 15) >> 3);
    const int celli = (lane & 7) >> 1;
    const int cellw = lane & 1;
    const u32 ebase = (u32)((rb * 4 + wv) * NCH + cellch) * 512u;

    float ct[2][4] = {};   // persistent cell state in registers

    for (int t = 0; t < SEQ; ++t) {
        const u64* Hq = (const u64*)((t & 1) ? H1 : H0);
        u32*       Np = (t & 1) ? H0 : H1;

        f32x4 acc[2][4] = {};   // [m][gate]
        u64 fr[3][8];           // A triple buffer: [buf][m*4+i]

#define ALOAD(f, ch) do { \
        _Pragma("unroll") \
        for (int m_ = 0; m_ < 2; ++m_) \
            _Pragma("unroll") \
            for (int i_ = 0; i_ < 4; ++i_) \
                f[m_ * 4 + i_] = __hip_atomic_load( \
                    &Hq[wbase + (u32)(ch) * 512u + (u32)m_ * 256u + (u32)i_ * 64u], \
                    __ATOMIC_RELAXED, __HIP_MEMORY_SCOPE_AGENT); } while (0)
#define WSOFF(cb, off) ((cb) * KL + (((off)) ^ (((cb) & 7) << 3)))
#define CCOMP(f, ch) do { \
        s16x8 ah0, al0, ah1, al1; \
        unpack16(*(const u32x4*)&f[0], *(const u32x4*)&f[2], &ah0, &al0); \
        unpack16(*(const u32x4*)&f[4], *(const u32x4*)&f[6], &ah1, &al1); \
        s16x8 bh[4], bl[4]; \
        _Pragma("unroll") \
        for (int n = 0; n < 4; ++n) { \
            bh[n] = *(const s16x8*)&Ws[WSOFF(n * 16 + (lane & 15), (ch) * 32 + akof)]; \
            bl[n] = *(const s16x8*)&Ws[WSOFF(64 + n * 16 + (lane & 15), (ch) * 32 + akof)]; \
        } \
        _Pragma("unroll") \
        for (int n = 0; n < 4; ++n) { \
            acc[0][n] = __builtin_amdgcn_mfma_f32_16x16x32_bf16(ah0, bh[n], acc[0][n], 0, 0, 0); \
            acc[0][n] = __builtin_amdgcn_mfma_f32_16x16x32_bf16(ah0, bl[n], acc[0][n], 0, 0, 0); \
            acc[0][n] = __builtin_amdgcn_mfma_f32_16x16x32_bf16(al0, bh[n], acc[0][n], 0, 0, 0); \
            acc[1][n] = __builtin_amdgcn_mfma_f32_16x16x32_bf16(ah1, bh[n], acc[1][n], 0, 0, 0); \
            acc[1][n] = __builtin_amdgcn_mfma_f32_16x16x32_bf16(ah1, bl[n], acc[1][n], 0, 0, 0); \
            acc[1][n] = __builtin_amdgcn_mfma_f32_16x16x32_bf16(al1, bh[n], acc[1][n], 0, 0, 0); \
        } } while (0)

        ALOAD(fr[0], 0); ALOAD(fr[1], 1);
        #pragma unroll
        for (int ch = 0; ch < NCH; ++ch) {
            if (ch + 2 < NCH) ALOAD(fr[(ch + 2) % 3], ch + 2);
            CCOMP(fr[ch % 3], ch);
        }
#undef ALOAD
#undef CCOMP

        // Fused gate epilogue; c in registers. TF gate order: i, j, f, o.
        #pragma unroll
        for (int m = 0; m < 2; ++m) {
            #pragma unroll
            for (int r = 0; r < 4; ++r) {
                int row = r0 + wv * 32 + m * 16 + (lane >> 4) * 4 + r;
                float zi = acc[m][0][r] + bi;
                float zj = acc[m][1][r] + bj;
                float zf = acc[m][2][r] + bf_;
                float zo = acc[m][3][r] + bo;
                float cn = ct[m][r] * sigm(zf + 1.0f) + sigm(zi) * ftanh(zj);
                ct[m][r] = cn;
                float h = ftanh(cn) * sigm(zo);
                u16 hh = f2b(h);
                u16 hl = f2b(h - b2f(hh));
                u32 pk = (u32)hh | ((u32)hl << 16);
                int lp = ((lane >> 4) << 2) + r + (cellsub << 4);
                u32 q = ebase + (u32)(m * 256 + celli * 64 + lp);
                __hip_atomic_store(&Np[q * 2u + (u32)cellw], pk,
                                   __ATOMIC_RELAXED, __HIP_MEMORY_SCOPE_AGENT);
                if (t == SEQ - 1) hf32[(size_t)row * NCELL + cell] = h;
            }
        }
        // Stage next step's x-slice into the next A plane (fragment-major).
        if (t + 1 < SEQ && nb < NFEAT && tid < 128) {
            int row = r0 + tid;
            float v = X[(size_t)row * (SEQ * NFEAT) + (t + 1) * NFEAT + nb];
            u16 vh = f2b(v), vl = f2b(v - b2f(vh));
            u32 pk = (u32)vh | ((u32)vl << 16);
            int wv2 = tid >> 5, m2 = (tid >> 4) & 1;
            int lp = (tid & 15) + ((nb >> 3) << 4);
            u32 q = (u32)((rb * 4 + wv2) * NCH + 16) * 512u
                  + (u32)(m2 * 256 + ((nb & 7) >> 1) * 64 + lp);
            __hip_atomic_store(&Np[q * 2u + (u32)(nb & 1)], pk,
                               __ATOMIC_RELAXED, __HIP_MEMORY_SCOPE_AGENT);
        }

        // ---- row-group barrier: pure atomics, NO cache maintenance ----
        __syncthreads();   // vmcnt drained: write-through stores visible at L3
        if (tid == 0) {
            int n = __hip_atomic_fetch_add(bcnt, 1, __ATOMIC_RELAXED, __HIP_MEMORY_SCOPE_AGENT);
            if (n == GWG - 1) {
                __hip_atomic_store(bcnt, 0, __ATOMIC_RELAXED, __HIP_MEMORY_SCOPE_AGENT);
                __hip_atomic_store(bepoch, t + 1, __ATOMIC_RELEASE, __HIP_MEMORY_SCOPE_AGENT);
            } else {
                int spins = 0;
                while (__hip_atomic_load(bepoch, __ATOMIC_RELAXED, __HIP_MEMORY_SCOPE_AGENT) <= t) {
                    __builtin_amdgcn_s_sleep(4);
                    if (++spins > 20000000) break;   // bail out instead of hanging
                }
            }
        }
        __syncthreads();
        // no fence: next step's H reads are read-through atomics (always coherent)
    }
}

// ---------- fp32 tail GEMM: C = act(A @ Wm + bias), tile 64x64 ----------
template <int ACT>
__global__ __launch_bounds__(256) void gemm64(
    const float* __restrict__ A, const float* __restrict__ Wm,
    const float* __restrict__ bias, float* __restrict__ out,
    int M, int N, int K)
{
    __shared__ float Asf[32][65];
    __shared__ float Bsf[32][65];
    const int c0 = blockIdx.x * 64;
    const int r0 = blockIdx.y * 64;
    const int tid = (int)threadIdx.x;
    const int tx = tid & 15, ty = tid >> 4;

    float acc[4][4];
    #pragma unroll
    for (int r = 0; r < 4; ++r) { acc[r][0]=0.f; acc[r][1]=0.f; acc[r][2]=0.f; acc[r][3]=0.f; }

    for (int k0 = 0; k0 < K; k0 += 32) {
        #pragma unroll
        for (int i = 0; i < 8; ++i) {
            int e = tid + 256 * i;
            int row = e >> 5, kk = e & 31;
            Asf[kk][row] = A[(size_t)(r0 + row) * K + k0 + kk];
        }
        #pragma unroll
        for (int i = 0; i < 8; ++i) {
            int e = tid + 256 * i;
            int kk = e >> 6, cl = e & 63;
            Bsf[kk][cl] = Wm[(size_t)(k0 + kk) * N + c0 + cl];
        }
        __syncthreads();
        #pragma unroll
        for (int kk = 0; kk < 32; ++kk) {
            float b0 = Bsf[kk][tx*4], b1 = Bsf[kk][tx*4+1], b2 = Bsf[kk][tx*4+2], b3 = Bsf[kk][tx*4+3];
            #pragma unroll
            for (int r = 0; r < 4; ++r) {
                float a = Asf[kk][ty*4 + r];
                acc[r][0] = fmaf(a, b0, acc[r][0]);
                acc[r][1] = fmaf(a, b1, acc[r][1]);
                acc[r][2] = fmaf(a, b2, acc[r][2]);
                acc[r][3] = fmaf(a, b3, acc[r][3]);
            }
        }
        __syncthreads();
    }
    #pragma unroll
    for (int r = 0; r < 4; ++r) {
        int gr = r0 + ty * 4 + r;
        #pragma unroll
        for (int j = 0; j < 4; ++j) {
            int gc = c0 + tx * 4 + j;
            float v = acc[r][j] + bias[gc];
            if (ACT) v = fmaxf(v, 0.f);
            out[(size_t)gr * N + gc] = v;
        }
    }
}

extern "C" void kernel_launch(void* const* d_in, const int* in_sizes, int n_in,
                              void* d_out, int out_size, void* d_ws, size_t ws_size,
                              hipStream_t stream)
{
    const float* X  = (const float*)d_in[0];
    const float* Wl = (const float*)d_in[1];
    const float* bl = (const float*)d_in[2];
    const float* Wd = (const float*)d_in[3];
    const float* bd = (const float*)d_in[4];
    const float* Wp = (const float*)d_in[5];
    const float* bp = (const float*)d_in[6];
    float* out = (float*)d_out;

    // ws layout
    char* p = (char*)d_ws;
    int* bar      = (int*)p; p += 4096;                              // 8 groups x 256 B
    float* hf32   = (float*)p; p += (size_t)BATCH * NCELL * 4;       // 2 MB
    float* dense  = (float*)p; p += (size_t)BATCH * DENSE_N * 4;     // 8 MB
    u16* Wthi = (u16*)p; p += (size_t)ZC * KP * 2;                   // 2.23 MB
    u16* Wtlo = (u16*)p; p += (size_t)ZC * KP * 2;
    u32* H0   = (u32*)p; p += (size_t)BATCH * KP * 4;                // 2.23 MB
    u32* H1   = (u32*)p; p += (size_t)BATCH * KP * 4;

    (void)hipMemsetAsync(bar, 0, 4096, stream);
    prep_w<<<(ZC * KP) / 256, 256, 0, stream>>>(Wl, Wthi, Wtlo);
    prep_h<<<(BATCH * KP) / 256, 256, 0, stream>>>(X, H0, H1);

    const int lds_bytes = 2 * 64 * KL * 2;   // 147456
    (void)hipFuncSetAttribute((const void*)lstm_persist,
                              hipFuncAttributeMaxDynamicSharedMemorySize, lds_bytes);
    lstm_persist<<<NWG, 256, lds_bytes, stream>>>(H0, H1, Wthi, Wtlo, bl, X, hf32, bar);

    dim3 blk(256);
    gemm64<1><<<dim3(DENSE_N / 64, BATCH / 64), blk, 0, stream>>>(hf32, Wd, bd, dense, BATCH, DENSE_N, NCELL);
    gemm64<0><<<dim3(PRED_N / 64, BATCH / 64), blk, 0, stream>>>(dense, Wp, bp, out, BATCH, PRED_N, DENSE_N);
}